// Round 9
// baseline (4840.313 us; speedup 1.0000x reference)
//
#include <hip/hip_runtime.h>

namespace {
constexpr int kB = 16, kT = 512, kIN = 16, kD = 128, kH = 256, kL = 136, kO = 32;
constexpr int kSteps = kT - 1;      // 511
constexpr int NBLK = 256;           // 0..127 MLP (8 per b) | 128..255 z3 (d = k-128)
constexpr int NTHR = 512;
constexpr int NMLPB = 128;
constexpr int NT3 = 9;              // z3 n-tiles of 16 (144 cols, 136 real)
// ---- z3-role LDS (bytes) ----
constexpr int OFF_W3L = 0;          // [9][8][64][8] f16 frags   73728
constexpr int OFF_Z2H = 73728;      // [16][272] f16              8704
constexpr int OFF_Z2L = 82432;      // [16][272] f16              8704
constexpr int OFF_OMS = 91136;      // [16][140] f32              8960
constexpr int OFF_RED = 100096;     // [16][8]  f32                512
constexpr size_t LDS_BYTES = 100608;
// ---- MLP-role LDS (aliases same arena) ----
constexpr int OFF_FW2 = 0;          // [32][260] f32             33280
constexpr int OFF_Z1S = 33280;      // [256] f32                  1024
constexpr int OFF_HB  = 34304;      // [128] f32                   512
constexpr int OFF_HHI = 34816;      // [128] f16                   256
constexpr int OFF_HLO = 35072;      // [128] f16                   256
}

typedef __attribute__((ext_vector_type(8))) _Float16 half8;
typedef __attribute__((ext_vector_type(4))) float f32x4;

__device__ __forceinline__ float softplusf(float x) {
  return fmaxf(x, 0.0f) + log1pf(expf(-fabsf(x)));
}
__device__ __forceinline__ unsigned short h2u(_Float16 h) {
  unsigned short u; __builtin_memcpy(&u, &h, 2); return u;
}
#define ALOAD64(p)    __hip_atomic_load((p),  __ATOMIC_RELAXED, __HIP_MEMORY_SCOPE_AGENT)
#define ASTORE64(p,v) __hip_atomic_store((p), (v), __ATOMIC_RELAXED, __HIP_MEMORY_SCOPE_AGENT)

__global__ void __launch_bounds__(256)
rde_init(const float* __restrict__ x0,
         const float* __restrict__ iw1, const float* __restrict__ ib1,
         const float* __restrict__ iw2, const float* __restrict__ ib2,
         const float* __restrict__ iw3, const float* __restrict__ ib3,
         float* __restrict__ hist) {
  __shared__ float xs[kIN];
  __shared__ __align__(16) float t1[kH];
  __shared__ __align__(16) float t2[kH];
  const int b = blockIdx.x, tid = threadIdx.x;
  if (tid < kIN) xs[tid] = x0[b*kIN + tid];
  __syncthreads();
  {
    float a = ib1[tid];
#pragma unroll
    for (int i = 0; i < kIN; ++i) a = fmaf(xs[i], iw1[tid*kIN + i], a);
    t1[tid] = softplusf(a);
  }
  __syncthreads();
  {
    const float4* wr = (const float4*)(iw2 + (size_t)tid*kH);
    float a = ib2[tid];
#pragma unroll 8
    for (int q = 0; q < kH/4; ++q) {
      float4 w = wr[q];
      a = fmaf(t1[4*q+0], w.x, a); a = fmaf(t1[4*q+1], w.y, a);
      a = fmaf(t1[4*q+2], w.z, a); a = fmaf(t1[4*q+3], w.w, a);
    }
    t2[tid] = softplusf(a);
  }
  __syncthreads();
  if (tid < kD) {
    const float4* wr = (const float4*)(iw3 + (size_t)tid*kH);
    float a = ib3[tid];
#pragma unroll 8
    for (int q = 0; q < kH/4; ++q) {
      float4 w = wr[q];
      a = fmaf(t2[4*q+0], w.x, a); a = fmaf(t2[4*q+1], w.y, a);
      a = fmaf(t2[4*q+2], w.z, a); a = fmaf(t2[4*q+3], w.w, a);
    }
    hist[(size_t)b*kD + tid] = a;
  }
}

__global__ void __launch_bounds__(NTHR, 1)
rde_scan(const float* __restrict__ lsg,
         const float* __restrict__ fw1, const float* __restrict__ fb1,
         const float* __restrict__ fw2, const float* __restrict__ fb2,
         const float* __restrict__ fw3, const float* __restrict__ fb3,
         float* __restrict__ hist,
         unsigned long long* z2x, unsigned long long* partx) {
  extern __shared__ char smem[];
  const int tid  = threadIdx.x;
  const int k    = blockIdx.x;
  const int wave = tid >> 6, lane = tid & 63;
  const int l15  = lane & 15, g = lane >> 4;

  if (k >= NMLPB) {
    // ================= z3 role: one d, all 136 l =================
    _Float16* W3L  = (_Float16*)(smem + OFF_W3L);
    _Float16* z2hi = (_Float16*)(smem + OFF_Z2H);
    _Float16* z2lo = (_Float16*)(smem + OFF_Z2L);
    float* oms = (float*)(smem + OFF_OMS);
    float* red = (float*)(smem + OFF_RED);
    const int d_own = k - NMLPB;

    // fw3 d-shard -> LDS fp16 fragments
    for (int i = tid; i < NT3*8*64; i += NTHR) {
      const int w = i >> 9, s = (i >> 6) & 7, ln = i & 63;
      const int nl = w*16 + (ln & 15), col = s*32 + (ln >> 4)*8;
      half8 hv;
      if (nl < kL) {
        const float* p = fw3 + ((size_t)d_own*kL + nl)*kH + col;
#pragma unroll
        for (int e = 0; e < 8; ++e) hv[e] = (_Float16)p[e];
      } else {
#pragma unroll
        for (int e = 0; e < 8; ++e) hv[e] = (_Float16)0.f;
      }
      *(half8*)(W3L + ((w*8 + s)*64 + ln)*8) = hv;
    }
    const float biasv = fb3[(size_t)d_own*kL + wave*16 + l15];
    const float bias8 = (wave == 7 && l15 < 8) ? fb3[(size_t)d_own*kL + 128 + l15] : 0.f;
    __syncthreads();

    for (int t = 0; t < kSteps; ++t) {
      const unsigned epw = (unsigned)(t + 1);
      // oms prefetch (overlaps z2 poll latency)
#pragma unroll 2
      for (int rep = 0; rep < 2; ++rep) {
        int cc = tid + rep*512;
        if (cc < 544) {
          int bb = cc / 34, ii = cc - bb*34;
          float4 v = *(const float4*)(lsg + ((size_t)bb*kSteps + t)*kL + ii*4);
          *(float4*)(oms + bb*140 + ii*4) = v;
        }
      }
      // poll z2 (epoch-embedded, self-validating)
      unsigned long long q8[8];
      {
        const unsigned long long* src = z2x + (size_t)tid*8;
        for (;;) {
          bool ok = true;
#pragma unroll
          for (int i = 0; i < 8; ++i) q8[i] = ALOAD64(src + i);
#pragma unroll
          for (int i = 0; i < 8; ++i) ok &= ((unsigned)(q8[i] >> 32) == epw);
          if (ok) break;
          __builtin_amdgcn_s_sleep(1);
        }
      }
      {
        const int e0 = tid*8, m = e0 >> 8, kk = e0 & 255;
        unsigned* ph = (unsigned*)(z2hi + m*272 + kk);
        unsigned* pl = (unsigned*)(z2lo + m*272 + kk);
#pragma unroll
        for (int i = 0; i < 4; ++i) {
          unsigned a = (unsigned)q8[2*i], b = (unsigned)q8[2*i+1];
          ph[i] = (a & 0xffffu) | (b << 16);
          pl[i] = (a >> 16) | (b & 0xffff0000u);
        }
      }
      __syncthreads();

      // MFMA: wave w -> tile w; wave 7 also tile 8
      f32x4 acc = {biasv, biasv, biasv, biasv};
      f32x4 acc8 = {bias8, bias8, bias8, bias8};
#pragma unroll
      for (int s = 0; s < 8; ++s) {
        half8 ah = *(const half8*)(z2hi + l15*272 + s*32 + g*8);
        half8 al = *(const half8*)(z2lo + l15*272 + s*32 + g*8);
        half8 bh = *(const half8*)(W3L + ((wave*8 + s)*64 + lane)*8);
        acc = __builtin_amdgcn_mfma_f32_16x16x32_f16(ah, bh, acc, 0, 0, 0);
        acc = __builtin_amdgcn_mfma_f32_16x16x32_f16(al, bh, acc, 0, 0, 0);
        if (wave == 7) {
          half8 b8 = *(const half8*)(W3L + ((64 + s)*64 + lane)*8);
          acc8 = __builtin_amdgcn_mfma_f32_16x16x32_f16(ah, b8, acc8, 0, 0, 0);
          acc8 = __builtin_amdgcn_mfma_f32_16x16x32_f16(al, b8, acc8, 0, 0, 0);
        }
      }
      // in-register contraction: tanh * logsig, reduce over the 16 l15 lanes
#pragma unroll
      for (int r = 0; r < 4; ++r) {
        const int b = g*4 + r;
        float p = tanhf(acc[r]) * oms[b*140 + wave*16 + l15];
        if (wave == 7 && l15 < 8)
          p += tanhf(acc8[r]) * oms[b*140 + 128 + l15];
        p += __shfl_xor(p, 1); p += __shfl_xor(p, 2);
        p += __shfl_xor(p, 4); p += __shfl_xor(p, 8);
        if (l15 == 0) red[b*8 + wave] = p;
      }
      __syncthreads();
      if (tid < 16) {
        float s = 0.f;
#pragma unroll
        for (int w = 0; w < 8; ++w) s += red[tid*8 + w];
        unsigned long long pk = (unsigned long long)__float_as_uint(s)
                              | ((unsigned long long)epw << 32);
        ASTORE64(partx + (size_t)tid*NMLPB + d_own, pk);   // partx[b][d]
      }
    }
  } else {
    // ================= MLP role: b = k>>3, z2 cols [j0, j0+32) =================
    float* fw2s = (float*)(smem + OFF_FW2);
    float* z1s  = (float*)(smem + OFF_Z1S);
    float* hb   = (float*)(smem + OFF_HB);
    _Float16* hhi = (_Float16*)(smem + OFF_HHI);
    _Float16* hlo = (_Float16*)(smem + OFF_HLO);
    const int b_own = k >> 3, e8 = k & 7, j0 = e8 * 32;

    // fw1 fp16 B-fragments in VGPR (2 n-tiles per wave = full 256 cols)
    half8 bw1[2][4];
    float fb1v[2];
#pragma unroll
    for (int ti = 0; ti < 2; ++ti) {
      const int n = (wave*2 + ti)*16 + l15;
      fb1v[ti] = fb1[n];
#pragma unroll
      for (int kst = 0; kst < 4; ++kst) {
        const float* p = fw1 + (size_t)n*kD + kst*32 + g*8;
        half8 h;
#pragma unroll
        for (int e = 0; e < 8; ++e) h[e] = (_Float16)p[e];
        bw1[ti][kst] = h;
      }
    }
    const float fb2v = fb2[j0 + (tid >> 4)];
    // fw2 32-col slice -> LDS f32 [32][260]
    for (int i = tid; i < 32*64; i += NTHR) {
      int jl = i >> 6, q = i & 63;
      float4 v = *(const float4*)(fw2 + (size_t)(j0 + jl)*kH + q*4);
      *(float4*)(fw2s + jl*260 + q*4) = v;
    }
    if (tid < kD) {
      float hv = hist[(size_t)b_own*kD + tid];
      hb[tid] = hv;
      _Float16 hh = (_Float16)hv;
      hhi[tid] = hh; hlo[tid] = (_Float16)(hv - (float)hh);
    }
    __syncthreads();

    for (int t = 0; t < kSteps; ++t) {
      const unsigned epw = (unsigned)(t + 1);
      // [A] z1 = softplus(h @ fw1^T), redundant full 256, MFMA fp16
      f32x4 a0 = {fb1v[0], fb1v[0], fb1v[0], fb1v[0]};
      f32x4 a1 = {fb1v[1], fb1v[1], fb1v[1], fb1v[1]};
#pragma unroll
      for (int kst = 0; kst < 4; ++kst) {
        half8 ah = *(const half8*)(hhi + kst*32 + g*8);
        half8 al = *(const half8*)(hlo + kst*32 + g*8);
        a0 = __builtin_amdgcn_mfma_f32_16x16x32_f16(ah, bw1[0][kst], a0, 0, 0, 0);
        a0 = __builtin_amdgcn_mfma_f32_16x16x32_f16(al, bw1[0][kst], a0, 0, 0, 0);
        a1 = __builtin_amdgcn_mfma_f32_16x16x32_f16(ah, bw1[1][kst], a1, 0, 0, 0);
        a1 = __builtin_amdgcn_mfma_f32_16x16x32_f16(al, bw1[1][kst], a1, 0, 0, 0);
      }
      if (g == 0) {
        z1s[(wave*2+0)*16 + l15] = softplusf(a0[0]);
        z1s[(wave*2+1)*16 + l15] = softplusf(a1[0]);
      }
      __syncthreads();
      // [B] z2 32-col slice, f32 VALU, publish epoch-embedded fp16 hi/lo
      {
        const int jl = tid >> 4, ks = tid & 15;
        float a = 0.f;
#pragma unroll
        for (int kh = ks; kh < kH; kh += 16)
          a = fmaf(z1s[kh], fw2s[jl*260 + kh], a);
        a += __shfl_xor(a, 1); a += __shfl_xor(a, 2);
        a += __shfl_xor(a, 4); a += __shfl_xor(a, 8);
        if (ks == 0) {
          float v = softplusf(a + fb2v);
          _Float16 vh = (_Float16)v;
          _Float16 vl = (_Float16)(v - (float)vh);
          unsigned long long pk =
              (unsigned long long)((unsigned)h2u(vh) | ((unsigned)h2u(vl) << 16))
            | ((unsigned long long)epw << 32);
          ASTORE64(z2x + b_own*kH + j0 + jl, pk);
        }
      }
      // [E] poll own-b partials (one per d), update h, repack fp16 planes
      if (tid < kD) {
        const unsigned long long* pp = partx + (size_t)b_own*NMLPB + tid;
        unsigned long long q;
        for (;;) {
          q = ALOAD64(pp);
          if ((unsigned)(q >> 32) == epw) break;
          __builtin_amdgcn_s_sleep(1);
        }
        float hn = hb[tid] + __uint_as_float((unsigned)q);
        hb[tid] = hn;
        if (e8 == 0) hist[((size_t)(t+1)*kB + b_own)*kD + tid] = hn;
        _Float16 hh = (_Float16)hn;
        hhi[tid] = hh; hlo[tid] = (_Float16)(hn - (float)hh);
      }
      __syncthreads();
    }
  }
}

__global__ void __launch_bounds__(512)
rde_readout(const float* __restrict__ hist, const float* __restrict__ rw,
            const float* __restrict__ rb, float* __restrict__ out) {
  const int t = blockIdx.x, tid = threadIdx.x;
  const int b = tid >> 5, o = tid & 31;
  const float4* hr = (const float4*)(hist + ((size_t)t*kB + b)*kD);
  const float4* wr = (const float4*)(rw + (size_t)o*kD);
  float a = rb[o];
#pragma unroll 8
  for (int q = 0; q < kD/4; ++q) {
    float4 h4 = hr[q], w4 = wr[q];
    a = fmaf(h4.x,w4.x,a); a = fmaf(h4.y,w4.y,a);
    a = fmaf(h4.z,w4.z,a); a = fmaf(h4.w,w4.w,a);
  }
  out[((size_t)b*kT + t)*kO + o] = a;
}

extern "C" void kernel_launch(void* const* d_in, const int* in_sizes, int n_in,
                              void* d_out, int out_size, void* d_ws, size_t ws_size,
                              hipStream_t stream) {
  const float* x0  = (const float*)d_in[0];
  const float* lsg = (const float*)d_in[1];
  const float* iw1 = (const float*)d_in[2];
  const float* ib1 = (const float*)d_in[3];
  const float* iw2 = (const float*)d_in[4];
  const float* ib2 = (const float*)d_in[5];
  const float* iw3 = (const float*)d_in[6];
  const float* ib3 = (const float*)d_in[7];
  const float* fw1 = (const float*)d_in[8];
  const float* fb1 = (const float*)d_in[9];
  const float* fw2 = (const float*)d_in[10];
  const float* fb2 = (const float*)d_in[11];
  const float* fw3 = (const float*)d_in[12];
  const float* fb3 = (const float*)d_in[13];
  const float* rw  = (const float*)d_in[14];
  const float* rb  = (const float*)d_in[15];
  float* out = (float*)d_out;

  float* hist = (float*)d_ws;                                  // 512*16*128 f32
  unsigned long long* z2x =
      (unsigned long long*)(hist + (size_t)kT*kB*kD);          // [16][256] u64
  unsigned long long* partx = z2x + (size_t)kB*kH;             // [16][128] u64

  hipMemsetAsync(z2x, 0, ((size_t)kB*kH + (size_t)kB*NMLPB)*8, stream);
  hipFuncSetAttribute((const void*)rde_scan,
                      hipFuncAttributeMaxDynamicSharedMemorySize, (int)LDS_BYTES);

  rde_init<<<kB, 256, 0, stream>>>(x0, iw1, ib1, iw2, ib2, iw3, ib3, hist);

  void* args[] = { (void*)&lsg, (void*)&fw1, (void*)&fb1, (void*)&fw2, (void*)&fb2,
                   (void*)&fw3, (void*)&fb3, (void*)&hist, (void*)&z2x, (void*)&partx };
  hipLaunchCooperativeKernel((const void*)rde_scan, dim3(NBLK), dim3(NTHR),
                             args, (unsigned)LDS_BYTES, stream);

  rde_readout<<<kT, 512, 0, stream>>>(hist, rw, rb, out);
}